// Round 4
// baseline (275.930 us; speedup 1.0000x reference)
//
#include <hip/hip_runtime.h>
#include <hip/hip_bf16.h>
#include <math.h>

typedef __attribute__((ext_vector_type(4))) float f32x4;
typedef __attribute__((ext_vector_type(8))) short bf16x8;     // 8 bf16 in 4 VGPRs
typedef __attribute__((ext_vector_type(4))) unsigned short u16x4;
typedef __attribute__((ext_vector_type(8))) unsigned short u16x8;

__device__ __forceinline__ unsigned short f2b(float f) {
  unsigned int u = __builtin_bit_cast(unsigned int, f);
  u += 0x7fffu + ((u >> 16) & 1u);          // RNE
  return (unsigned short)(u >> 16);
}
__device__ __forceinline__ float b2f(unsigned short u) {
  unsigned int v = ((unsigned int)u) << 16;
  return __builtin_bit_cast(float, v);
}
__device__ __forceinline__ float gelu_exact(float x) {
  return 0.5f * x * (1.0f + erff(x * 0.70710678118654752440f));
}
__device__ __forceinline__ void gload_lds16(const void* g, void* l) {
  __builtin_amdgcn_global_load_lds((const __attribute__((address_space(1))) void*)g,
                                   (__attribute__((address_space(3))) void*)l,
                                   16, 0, 0);
}
#define SB  __builtin_amdgcn_sched_barrier(0)
#define BARRIER do { SB; __builtin_amdgcn_s_barrier(); SB; } while (0)

// ---------------- x: f32 -> bf16 ----------------
__global__ void convert_x(const float* __restrict__ x, unsigned short* __restrict__ xb, int n4) {
  int stride = gridDim.x * blockDim.x;
  for (int i = blockIdx.x * blockDim.x + threadIdx.x; i < n4; i += stride) {
    f32x4 v = ((const f32x4*)x)[i];
    u16x4 o;
    o[0] = f2b(v[0]); o[1] = f2b(v[1]); o[2] = f2b(v[2]); o[3] = f2b(v[3]);
    ((u16x4*)xb)[i] = o;
  }
}

// ---------------- token hidden: hk = gelu(tokens@Wk1), hv = gelu(tokens@Wv1) ----------------
__global__ void token_h(const float* __restrict__ tokens,
                        const float* __restrict__ Wk1, const float* __restrict__ Wv1,
                        float* __restrict__ hk, float* __restrict__ hv) {
  __shared__ float tok[4][64];
  const int tid = threadIdx.x;
  const int tl = tid >> 6, j = tid & 63;
  const int t0 = blockIdx.x * 4;
  tok[tl][j] = tokens[(size_t)(t0 + tl) * 64 + j];
  __syncthreads();
  float sk = 0.f, sv = 0.f;
  #pragma unroll 16
  for (int i = 0; i < 64; ++i) {
    float tv = tok[tl][i];
    sk += tv * Wk1[i * 64 + j];
    sv += tv * Wv1[i * 64 + j];
  }
  hk[(size_t)(t0 + tl) * 64 + j] = gelu_exact(sk);
  hv[(size_t)(t0 + tl) * 64 + j] = gelu_exact(sv);
}

// ---------------- token proj: out[t,c] = sum_j h[t,j] * W2[j,c]  (bf16 out) ----------------
__global__ void token_proj(const float* __restrict__ hk, const float* __restrict__ hv,
                           const float* __restrict__ Wk2, const float* __restrict__ Wv2,
                           unsigned short* __restrict__ keyb, unsigned short* __restrict__ valb) {
  const float* h  = blockIdx.z ? hv : hk;
  const float* W2 = blockIdx.z ? Wv2 : Wk2;
  unsigned short* out = blockIdx.z ? valb : keyb;
  __shared__ float sh[16][64];
  const int tid = threadIdx.x;
  const int c  = blockIdx.x * 256 + tid;
  const int t0 = blockIdx.y * 16;
  #pragma unroll
  for (int i = 0; i < 4; ++i) {
    int idx = i * 256 + tid;
    sh[idx >> 6][idx & 63] = h[(size_t)t0 * 64 + idx];
  }
  __syncthreads();
  float a[16] = {};
  #pragma unroll 8
  for (int j = 0; j < 64; ++j) {
    float w = W2[(size_t)j * 2048 + c];
    #pragma unroll
    for (int t = 0; t < 16; ++t) a[t] += sh[t][j] * w;
  }
  #pragma unroll
  for (int t = 0; t < 16; ++t)
    out[(size_t)(t0 + t) * 2048 + c] = f2b(a[t]);
}

// ---------------- value [1024,2048] -> Vt [2048,1024] ----------------
__global__ void transpose_v(const unsigned short* __restrict__ val,
                            unsigned short* __restrict__ vt) {
  __shared__ unsigned short t[64][66];
  const int f0 = blockIdx.x * 64, t0 = blockIdx.y * 64;
  const int tid = threadIdx.x;
  for (int i = 0; i < 16; ++i) {
    int idx = i * 256 + tid; int r = idx >> 6, c = idx & 63;
    t[r][c] = val[(size_t)(t0 + r) * 2048 + f0 + c];
  }
  __syncthreads();
  for (int i = 0; i < 16; ++i) {
    int idx = i * 256 + tid; int r = idx >> 6, c = idx & 63;
    vt[(size_t)(f0 + r) * 1024 + t0 + c] = t[c][r];
  }
}

// ---------------- staging: one 128x64 bf16 HALF-tile, T2-swizzled via global source ----------------
// LDS linear dest; global col16 pre-XORed: LDS(r,c16) = G(r, c16 ^ (r&7)).
// 2 loads/thread @ 512 threads = 16 KB.
template<int LDK>
__device__ __forceinline__ void stage_half(const unsigned short* __restrict__ g, int row0,
                                           int k0, unsigned short* lds, int tid, int wave) {
  #pragma unroll
  for (int j = 0; j < 2; ++j) {
    int lin = j * 512 + tid;
    int rl  = lin >> 3;                       // 0..127
    int c16 = (lin & 7) ^ (rl & 7);
    gload_lds16(g + (size_t)(row0 + rl) * LDK + k0 + c16 * 8,
                lds + (j * 512 + wave * 64) * 8);
  }
}

// fragment reads (swizzled): G col16 = kk*4+q  ->  LDS col16 = (kk*4+q) ^ (r&7)
__device__ __forceinline__ void rd_A(const unsigned short* base, int wm, int lrow, int q,
                                     int mh, bf16x8 af[4][2]) {
  #pragma unroll
  for (int mi = 0; mi < 4; ++mi) {
    int r = wm * 128 + (mh + mi) * 16 + lrow;
    #pragma unroll
    for (int kk = 0; kk < 2; ++kk)
      af[mi][kk] = *(const bf16x8*)(base + r * 64 + (((kk * 4 + q) ^ (r & 7)) << 3));
  }
}
__device__ __forceinline__ void rd_B(const unsigned short* base, int wn, int lrow, int q,
                                     int nh, bf16x8 bb[2][2]) {
  #pragma unroll
  for (int ni = 0; ni < 2; ++ni) {
    int r = wn * 64 + (nh + ni) * 16 + lrow;
    #pragma unroll
    for (int kk = 0; kk < 2; ++kk)
      bb[ni][kk] = *(const bf16x8*)(base + r * 64 + (((kk * 4 + q) ^ (r & 7)) << 3));
  }
}
__device__ __forceinline__ void mfma_q(f32x4 acc[8][4], const bf16x8 af[4][2],
                                       const bf16x8 bb[2][2], int mh, int noff) {
  __builtin_amdgcn_s_setprio(1);
  #pragma unroll
  for (int mi = 0; mi < 4; ++mi)
    #pragma unroll
    for (int ni = 0; ni < 2; ++ni)
      #pragma unroll
      for (int kk = 0; kk < 2; ++kk)
        acc[mh + mi][noff + ni] =
            __builtin_amdgcn_mfma_f32_16x16x32_bf16(af[mi][kk], bb[ni][kk],
                                                    acc[mh + mi][noff + ni], 0, 0, 0);
  __builtin_amdgcn_s_setprio(0);
}

// ---------------- GEMM: C[M,N] = A[M,K] @ B[N,K]^T, bf16 in, f32 acc ----------------
// 256x256 tile, BK=64, 8 waves (2Mx4N). 8-phase m201-style schedule:
// iteration = 2 K-tiles (bufE, bufO static). Per phase: {reads | stage 1 half-tile |
// barrier | 16-MFMA quadrant | barrier}; vmcnt(4) only at phases 4 and 8.
// Stage slot audit: slot's last reader passes an end-phase barrier before the stage issues;
// every staged slot covered by a vmcnt >=2 phases after issue.
template<int K, int N, int OUTB>
__global__ __launch_bounds__(512, 2)
void gemm256(const unsigned short* __restrict__ A, const unsigned short* __restrict__ B,
             void* __restrict__ Cptr) {
  __shared__ unsigned short sm[65536];        // AE | BE | AO | BO, each 256x64
  const int tid  = threadIdx.x;
  const int wave = tid >> 6, lane = tid & 63;
  const int wm = wave >> 2, wn = wave & 3;
  const int lrow = lane & 15, q = lane >> 4;

  // T1: bijective XCD swizzle (nwg % 8 == 0)
  const int per = gridDim.x >> 3;
  const int swz = (blockIdx.x & 7) * per + (blockIdx.x >> 3);
  constexpr int NT = N >> 8;
  const int m0 = (swz / NT) << 8, n0 = (swz % NT) << 8;

  constexpr int NS = K >> 6;                  // K-tiles (even)
  constexpr int NI = NS >> 1;

  unsigned short* AE = sm;
  unsigned short* BE = sm + 16384;
  unsigned short* AO = sm + 32768;
  unsigned short* BO = sm + 49152;

  // prologue: tile0 A+B, tile1 B (tile1 A staged in-loop at P1/P2)
  stage_half<K>(A, m0,        0, AE,        tid, wave);
  stage_half<K>(A, m0 + 128,  0, AE + 8192, tid, wave);
  stage_half<K>(B, n0,        0, BE,        tid, wave);
  stage_half<K>(B, n0 + 128,  0, BE + 8192, tid, wave);
  stage_half<K>(B, n0,       64, BO,        tid, wave);
  stage_half<K>(B, n0 + 128, 64, BO + 8192, tid, wave);
  asm volatile("s_waitcnt vmcnt(4)" ::: "memory");   // tile0 landed; BO in flight
  BARRIER;

  f32x4 acc[8][4] = {};
  bf16x8 af[4][2], b0[2][2], b1[2][2];

  #pragma unroll 1
  for (int it = 0; it < NI; ++it) {
    const int kO  = (2 * it + 1) << 6;
    const int kE2 = (2 * it + 2) << 6;
    const int kO2 = (2 * it + 3) << 6;
    const bool pfE = (2 * it + 2) < NS;
    const bool pfO = (2 * it + 3) < NS;

    // ========== even K-tile (bufE) ==========
    // P1: read A mi0-3 + B ni0-1 | stage A-O-lo (read at P5; vmcnt@P4)
    rd_A(AE, wm, lrow, q, 0, af);
    rd_B(BE, wn, lrow, q, 0, b0);
    stage_half<K>(A, m0, kO, AO, tid, wave);
    BARRIER;
    mfma_q(acc, af, b0, 0, 0);
    BARRIER;
    // P2: read B ni2-3 | stage A-O-hi
    rd_B(BE, wn, lrow, q, 2, b1);
    stage_half<K>(A, m0 + 128, kO, AO + 8192, tid, wave);
    BARRIER;
    mfma_q(acc, af, b1, 0, 2);
    BARRIER;
    // P3: read A mi4-7 | stage B-E-lo(e+2) (BE b-reads done after P2 barrier)
    rd_A(AE, wm, lrow, q, 4, af);
    if (pfE) stage_half<K>(B, n0, kE2, BE, tid, wave);
    BARRIER;
    mfma_q(acc, af, b1, 4, 2);
    BARRIER;
    // P4: no reads | stage B-E-hi | vmcnt gate for bufO consumption
    if (pfE) {
      stage_half<K>(B, n0 + 128, kE2, BE + 8192, tid, wave);
      asm volatile("s_waitcnt vmcnt(4)" ::: "memory");   // A-O + older landed; B-E(4) in flight
    } else {
      asm volatile("s_waitcnt vmcnt(0)" ::: "memory");   // tail: drain A-O
    }
    BARRIER;
    mfma_q(acc, af, b0, 4, 0);
    BARRIER;

    // ========== odd K-tile (bufO) ==========
    // P5: read A mi0-3 + B ni0-1 | stage A-E-lo(e+2) (AE reads done after P3 barrier)
    rd_A(AO, wm, lrow, q, 0, af);
    rd_B(BO, wn, lrow, q, 0, b0);
    if (pfE) stage_half<K>(A, m0, kE2, AE, tid, wave);
    BARRIER;
    mfma_q(acc, af, b0, 0, 0);
    BARRIER;
    // P6: read B ni2-3 | stage A-E-hi
    rd_B(BO, wn, lrow, q, 2, b1);
    if (pfE) stage_half<K>(A, m0 + 128, kE2, AE + 8192, tid, wave);
    BARRIER;
    mfma_q(acc, af, b1, 0, 2);
    BARRIER;
    // P7: read A mi4-7 | stage B-O-lo(o+2) (BO b-reads done after P6 barrier)
    rd_A(AO, wm, lrow, q, 4, af);
    if (pfO) stage_half<K>(B, n0, kO2, BO, tid, wave);
    BARRIER;
    mfma_q(acc, af, b1, 4, 2);
    BARRIER;
    // P8: no reads | stage B-O-hi | vmcnt gate for bufE consumption next iter
    if (pfO) {
      stage_half<K>(B, n0 + 128, kO2, BO + 8192, tid, wave);
      asm volatile("s_waitcnt vmcnt(4)" ::: "memory");   // E-stages landed; B-O(4) in flight
    } else {
      asm volatile("s_waitcnt vmcnt(0)" ::: "memory");
    }
    BARRIER;
    mfma_q(acc, af, b0, 4, 0);
    BARRIER;
  }

  // ---- epilogue: C/D layout col=lane&15, row=(lane>>4)*4+reg ----
  if (OUTB) {
    unsigned short* C = (unsigned short*)Cptr;
    #pragma unroll
    for (int mi = 0; mi < 8; ++mi)
      #pragma unroll
      for (int ni = 0; ni < 4; ++ni) {
        int row = m0 + wm * 128 + mi * 16 + q * 4;
        int col = n0 + wn * 64 + ni * 16 + lrow;
        #pragma unroll
        for (int r = 0; r < 4; ++r)
          C[(size_t)(row + r) * N + col] = f2b(acc[mi][ni][r]);
      }
  } else {
    float* C = (float*)Cptr;
    #pragma unroll
    for (int mi = 0; mi < 8; ++mi)
      #pragma unroll
      for (int ni = 0; ni < 4; ++ni) {
        int row = m0 + wm * 128 + mi * 16 + q * 4;
        int col = n0 + wn * 64 + ni * 16 + lrow;
        #pragma unroll
        for (int r = 0; r < 4; ++r)
          C[(size_t)(row + r) * N + col] = acc[mi][ni][r];
      }
  }
}

// ---------------- row-wise RMS scale + gelu, in-place on bf16 sim ----------------
__global__ void norm_gelu_rows(unsigned short* __restrict__ sim) {
  const int row  = blockIdx.x * 4 + (threadIdx.x >> 6);
  const int lane = threadIdx.x & 63;
  unsigned short* p = sim + (size_t)row * 1024;
  u16x8 v0 = *(const u16x8*)&p[lane * 8];
  u16x8 v1 = *(const u16x8*)&p[512 + lane * 8];
  float f0[8], f1[8];
  float s = 0.f;
  #pragma unroll
  for (int j = 0; j < 8; ++j) { f0[j] = b2f(v0[j]); s += f0[j] * f0[j]; }
  #pragma unroll
  for (int j = 0; j < 8; ++j) { f1[j] = b2f(v1[j]); s += f1[j] * f1[j]; }
  #pragma unroll
  for (int off = 32; off >= 1; off >>= 1) s += __shfl_xor(s, off, 64);
  float scale = 32.0f * rsqrtf(fmaxf(s, 1e-20f));
  u16x8 o0, o1;
  #pragma unroll
  for (int j = 0; j < 8; ++j) o0[j] = f2b(gelu_exact(f0[j] * scale));
  #pragma unroll
  for (int j = 0; j < 8; ++j) o1[j] = f2b(gelu_exact(f1[j] * scale));
  *(u16x8*)&p[lane * 8] = o0;
  *(u16x8*)&p[512 + lane * 8] = o1;
}

extern "C" void kernel_launch(void* const* d_in, const int* in_sizes, int n_in,
                              void* d_out, int out_size, void* d_ws, size_t ws_size,
                              hipStream_t stream) {
  const float* x      = (const float*)d_in[0];
  const float* tokens = (const float*)d_in[1];
  const float* Wk1    = (const float*)d_in[2];
  const float* Wk2    = (const float*)d_in[3];
  const float* Wv1    = (const float*)d_in[4];
  const float* Wv2    = (const float*)d_in[5];

  char* ws = (char*)d_ws;
  unsigned short* xb   = (unsigned short*)(ws);                              // 64 MB
  unsigned short* keyb = (unsigned short*)(ws + (size_t)64 * 1024 * 1024);   // 4 MB
  unsigned short* valb = (unsigned short*)(ws + (size_t)68 * 1024 * 1024);   // 4 MB
  unsigned short* vtb  = (unsigned short*)(ws + (size_t)72 * 1024 * 1024);   // 4 MB
  unsigned short* simb = (unsigned short*)(ws + (size_t)76 * 1024 * 1024);   // 32 MB
  // hk/hv (256 KB each) alias the simb region: dead before gemm1 writes simb.
  float* hk = (float*)(ws + (size_t)76 * 1024 * 1024);
  float* hv = (float*)(ws + (size_t)77 * 1024 * 1024);

  hipLaunchKernelGGL(convert_x, dim3(2048), dim3(256), 0, stream, x, xb, 33554432 / 4);
  hipLaunchKernelGGL(token_h, dim3(256), dim3(256), 0, stream, tokens, Wk1, Wv1, hk, hv);
  hipLaunchKernelGGL(token_proj, dim3(8, 64, 2), dim3(256), 0, stream,
                     hk, hv, Wk2, Wv2, keyb, valb);
  hipLaunchKernelGGL(transpose_v, dim3(32, 16), dim3(256), 0, stream, valb, vtb);
  hipLaunchKernelGGL((gemm256<2048, 1024, 1>), dim3(256), dim3(512), 0, stream,
                     xb, keyb, (void*)simb);
  hipLaunchKernelGGL(norm_gelu_rows, dim3(4096), dim3(256), 0, stream, simb);
  hipLaunchKernelGGL((gemm256<1024, 2048, 0>), dim3(512), dim3(512), 0, stream,
                     simb, vtb, d_out);
}

// Round 6
// 143.852 us; speedup vs baseline: 1.9182x; 1.9182x over previous
//
#include <hip/hip_runtime.h>
#include <hip/hip_bf16.h>
#include <math.h>

typedef __attribute__((ext_vector_type(4))) float f32x4;
typedef __attribute__((ext_vector_type(8))) short bf16x8;     // 8 bf16 in 4 VGPRs
typedef __attribute__((ext_vector_type(4))) unsigned short u16x4;
typedef __attribute__((ext_vector_type(8))) unsigned short u16x8;

__device__ __forceinline__ unsigned short f2b(float f) {
  unsigned int u = __builtin_bit_cast(unsigned int, f);
  u += 0x7fffu + ((u >> 16) & 1u);          // RNE
  return (unsigned short)(u >> 16);
}
__device__ __forceinline__ float b2f(unsigned short u) {
  unsigned int v = ((unsigned int)u) << 16;
  return __builtin_bit_cast(float, v);
}
__device__ __forceinline__ float gelu_exact(float x) {
  return 0.5f * x * (1.0f + erff(x * 0.70710678118654752440f));
}

// ---------------- token hidden + bf16 outputs ----------------
// hkb[t,j] = bf16(gelu(tokens@Wk1))  [1024,64]  (B-operand layout for sim)
// hvTb[j,t] = bf16(gelu(tokens@Wv1))ᵀ [64,1024] (B-operand layout for wv)
__global__ void token_h(const float* __restrict__ tokens,
                        const float* __restrict__ Wk1, const float* __restrict__ Wv1,
                        unsigned short* __restrict__ hkb, unsigned short* __restrict__ hvTb) {
  __shared__ float tok[4][64];
  const int tid = threadIdx.x;
  const int tl = tid >> 6, j = tid & 63;
  const int t0 = blockIdx.x * 4;
  tok[tl][j] = tokens[(size_t)(t0 + tl) * 64 + j];
  __syncthreads();
  float sk = 0.f, sv = 0.f;
  #pragma unroll 16
  for (int i = 0; i < 64; ++i) {
    float tv = tok[tl][i];
    sk += tv * Wk1[i * 64 + j];
    sv += tv * Wv1[i * 64 + j];
  }
  hkb[(size_t)(t0 + tl) * 64 + j]  = f2b(gelu_exact(sk));
  hvTb[(size_t)j * 1024 + t0 + tl] = f2b(gelu_exact(sv));
}

// ---------------- prep: Wk2 -> bf16 [64,2048]; Wv2 [64,2048] -> Wv2T bf16 [2048,64] ----------------
__global__ void prep_w(const float* __restrict__ Wk2, const float* __restrict__ Wv2,
                       unsigned short* __restrict__ Wk2b, unsigned short* __restrict__ Wv2Tb) {
  const int tid = threadIdx.x;
  if (blockIdx.x < 16) {
    // convert Wk2: 131072 elems = 32768 vec4; 16 blocks x 256 thr x 8
    for (int i = 0; i < 8; ++i) {
      int idx = blockIdx.x * 2048 + i * 256 + tid;          // coalesced
      f32x4 v = ((const f32x4*)Wk2)[idx];
      u16x4 o; o[0] = f2b(v[0]); o[1] = f2b(v[1]); o[2] = f2b(v[2]); o[3] = f2b(v[3]);
      ((u16x4*)Wk2b)[idx] = o;
    }
  } else {
    // transpose Wv2 tile: 64 j x 64 f
    __shared__ float t[64][65];
    const int f0 = (blockIdx.x - 16) * 64;
    for (int i = 0; i < 16; ++i) {
      int idx = i * 256 + tid; int r = idx >> 6, c = idx & 63;   // r=j, c=f
      t[r][c] = Wv2[(size_t)r * 2048 + f0 + c];
    }
    __syncthreads();
    for (int i = 0; i < 16; ++i) {
      int idx = i * 256 + tid; int r = idx >> 6, c = idx & 63;   // r=f, c=j
      Wv2Tb[(size_t)(f0 + r) * 64 + c] = f2b(t[c][r]);
    }
  }
}

// ---------------- skinny GEMM: out[M,64] bf16 = A[M,K] @ B[64,K]^T ----------------
// 16-row blocks, 4 waves split K into quarters, LDS cross-wave reduce.
// A read directly from global (f32 with in-reg convert, or bf16); B L2-resident.
template<int K, bool AF32>
__global__ __launch_bounds__(256)
void skinny64(const void* __restrict__ Aptr, const unsigned short* __restrict__ Bb,
              unsigned short* __restrict__ outp) {
  __shared__ float red[4][4][64][4];
  const int tid = threadIdx.x;
  const int wave = tid >> 6, lane = tid & 63;
  const int lrow = lane & 15, q = lane >> 4;
  const int r0 = blockIdx.x * 16;
  constexpr int KQ = K / 4;
  constexpr int NSTEP = KQ / 64;
  const int kbase = wave * KQ;

  f32x4 acc[4] = {};

  #pragma unroll
  for (int s = 0; s < NSTEP; ++s) {
    const int k0 = kbase + s * 64;
    bf16x8 a[2];
    if constexpr (AF32) {
      const float* A = (const float*)Aptr;
      #pragma unroll
      for (int kk = 0; kk < 2; ++kk) {
        const float* p = &A[(size_t)(r0 + lrow) * K + k0 + kk * 32 + q * 8];
        f32x4 lo = *(const f32x4*)p;
        f32x4 hi = *(const f32x4*)(p + 4);
        u16x8 t;
        t[0] = f2b(lo[0]); t[1] = f2b(lo[1]); t[2] = f2b(lo[2]); t[3] = f2b(lo[3]);
        t[4] = f2b(hi[0]); t[5] = f2b(hi[1]); t[6] = f2b(hi[2]); t[7] = f2b(hi[3]);
        a[kk] = __builtin_bit_cast(bf16x8, t);
      }
    } else {
      const unsigned short* A = (const unsigned short*)Aptr;
      #pragma unroll
      for (int kk = 0; kk < 2; ++kk)
        a[kk] = *(const bf16x8*)&A[(size_t)(r0 + lrow) * K + k0 + kk * 32 + q * 8];
    }
    #pragma unroll
    for (int nt = 0; nt < 4; ++nt) {
      #pragma unroll
      for (int kk = 0; kk < 2; ++kk) {
        bf16x8 b = *(const bf16x8*)&Bb[(size_t)(nt * 16 + lrow) * K + k0 + kk * 32 + q * 8];
        acc[nt] = __builtin_amdgcn_mfma_f32_16x16x32_bf16(a[kk], b, acc[nt], 0, 0, 0);
      }
    }
  }

  #pragma unroll
  for (int nt = 0; nt < 4; ++nt)
    *(f32x4*)&red[wave][nt][lane][0] = acc[nt];
  __syncthreads();
  if (wave == 0) {
    #pragma unroll
    for (int nt = 0; nt < 4; ++nt) {
      f32x4 s0 = *(const f32x4*)&red[0][nt][lane][0];
      f32x4 s1 = *(const f32x4*)&red[1][nt][lane][0];
      f32x4 s2 = *(const f32x4*)&red[2][nt][lane][0];
      f32x4 s3 = *(const f32x4*)&red[3][nt][lane][0];
      f32x4 s = s0 + s1 + s2 + s3;
      #pragma unroll
      for (int r = 0; r < 4; ++r)
        outp[(size_t)(r0 + q * 4 + r) * 64 + nt * 16 + lrow] = f2b(s[r]);
    }
  }
}

// ---------------- fused: sim = gelu(rownorm(xp @ hkb^T)) -> bf16 [16384,1024] ----------------
// 32-row blocks (512); 4 waves x 256-col stripes; full row in-block -> fused RMS norm.
__global__ __launch_bounds__(256)
void simw_norm(const unsigned short* __restrict__ xp, const unsigned short* __restrict__ hkb,
               unsigned short* __restrict__ simw) {
  __shared__ float red[4][32];
  const int tid = threadIdx.x;
  const int wave = tid >> 6, lane = tid & 63;
  const int lrow = lane & 15, q = lane >> 4;
  const int r0 = blockIdx.x * 32;

  bf16x8 a[2][2];
  #pragma unroll
  for (int mi = 0; mi < 2; ++mi)
    #pragma unroll
    for (int kk = 0; kk < 2; ++kk)
      a[mi][kk] = *(const bf16x8*)&xp[(size_t)(r0 + mi * 16 + lrow) * 64 + kk * 32 + q * 8];

  f32x4 acc[2][16] = {};
  #pragma unroll
  for (int nt = 0; nt < 16; ++nt) {
    const int trow = wave * 256 + nt * 16 + lrow;
    bf16x8 b0 = *(const bf16x8*)&hkb[(size_t)trow * 64 + q * 8];
    bf16x8 b1 = *(const bf16x8*)&hkb[(size_t)trow * 64 + 32 + q * 8];
    #pragma unroll
    for (int mi = 0; mi < 2; ++mi) {
      acc[mi][nt] = __builtin_amdgcn_mfma_f32_16x16x32_bf16(a[mi][0], b0, acc[mi][nt], 0, 0, 0);
      acc[mi][nt] = __builtin_amdgcn_mfma_f32_16x16x32_bf16(a[mi][1], b1, acc[mi][nt], 0, 0, 0);
    }
  }

  // row sum-of-squares: per-lane partial over 16 nt, reduce over lrow (lane bits 0..3), then cross-wave
  float part[2][4];
  #pragma unroll
  for (int mi = 0; mi < 2; ++mi)
    #pragma unroll
    for (int r = 0; r < 4; ++r) {
      float s = 0.f;
      #pragma unroll
      for (int nt = 0; nt < 16; ++nt) s += acc[mi][nt][r] * acc[mi][nt][r];
      part[mi][r] = s;
    }
  #pragma unroll
  for (int off = 1; off <= 8; off <<= 1)
    #pragma unroll
    for (int mi = 0; mi < 2; ++mi)
      #pragma unroll
      for (int r = 0; r < 4; ++r)
        part[mi][r] += __shfl_xor(part[mi][r], off, 64);
  if (lrow == 0) {
    #pragma unroll
    for (int mi = 0; mi < 2; ++mi)
      #pragma unroll
      for (int r = 0; r < 4; ++r)
        red[wave][mi * 16 + q * 4 + r] = part[mi][r];
  }
  __syncthreads();
  float scale[2][4];
  #pragma unroll
  for (int mi = 0; mi < 2; ++mi)
    #pragma unroll
    for (int r = 0; r < 4; ++r) {
      int rr = mi * 16 + q * 4 + r;
      float t = red[0][rr] + red[1][rr] + red[2][rr] + red[3][rr];
      scale[mi][r] = 32.0f * rsqrtf(fmaxf(t, 1e-20f));
    }

  #pragma unroll
  for (int mi = 0; mi < 2; ++mi)
    #pragma unroll
    for (int nt = 0; nt < 16; ++nt)
      #pragma unroll
      for (int r = 0; r < 4; ++r)
        simw[(size_t)(r0 + mi * 16 + q * 4 + r) * 1024 + wave * 256 + nt * 16 + lrow] =
            f2b(gelu_exact(acc[mi][nt][r] * scale[mi][r]));
}

// ---------------- out[16384,2048] f32 = wv[16384,64] @ Wv2T[2048,64]^T ----------------
// 32-row blocks (512); 4 waves x 512-col stripes; 128-col acc chunks.
__global__ __launch_bounds__(256)
void outk(const unsigned short* __restrict__ wv, const unsigned short* __restrict__ Wv2Tb,
          float* __restrict__ out) {
  const int tid = threadIdx.x;
  const int wave = tid >> 6, lane = tid & 63;
  const int lrow = lane & 15, q = lane >> 4;
  const int r0 = blockIdx.x * 32;
  const int c0 = wave * 512;

  bf16x8 a[2][2];
  #pragma unroll
  for (int mi = 0; mi < 2; ++mi)
    #pragma unroll
    for (int kk = 0; kk < 2; ++kk)
      a[mi][kk] = *(const bf16x8*)&wv[(size_t)(r0 + mi * 16 + lrow) * 64 + kk * 32 + q * 8];

  #pragma unroll 1
  for (int nf = 0; nf < 4; ++nf) {
    f32x4 acc[2][8] = {};
    #pragma unroll
    for (int nt = 0; nt < 8; ++nt) {
      const int frow = c0 + nf * 128 + nt * 16 + lrow;
      bf16x8 b0 = *(const bf16x8*)&Wv2Tb[(size_t)frow * 64 + q * 8];
      bf16x8 b1 = *(const bf16x8*)&Wv2Tb[(size_t)frow * 64 + 32 + q * 8];
      #pragma unroll
      for (int mi = 0; mi < 2; ++mi) {
        acc[mi][nt] = __builtin_amdgcn_mfma_f32_16x16x32_bf16(a[mi][0], b0, acc[mi][nt], 0, 0, 0);
        acc[mi][nt] = __builtin_amdgcn_mfma_f32_16x16x32_bf16(a[mi][1], b1, acc[mi][nt], 0, 0, 0);
      }
    }
    #pragma unroll
    for (int mi = 0; mi < 2; ++mi)
      #pragma unroll
      for (int nt = 0; nt < 8; ++nt)
        #pragma unroll
        for (int r = 0; r < 4; ++r)
          out[(size_t)(r0 + mi * 16 + q * 4 + r) * 2048 + c0 + nf * 128 + nt * 16 + lrow] =
              acc[mi][nt][r];
  }
}

extern "C" void kernel_launch(void* const* d_in, const int* in_sizes, int n_in,
                              void* d_out, int out_size, void* d_ws, size_t ws_size,
                              hipStream_t stream) {
  (void)in_sizes; (void)n_in; (void)out_size; (void)ws_size;
  const float* x      = (const float*)d_in[0];
  const float* tokens = (const float*)d_in[1];
  const float* Wk1    = (const float*)d_in[2];
  const float* Wk2    = (const float*)d_in[3];
  const float* Wv1    = (const float*)d_in[4];
  const float* Wv2    = (const float*)d_in[5];

  char* ws = (char*)d_ws;
  unsigned short* xp    = (unsigned short*)(ws);                                  // 2 MB
  unsigned short* wv    = (unsigned short*)(ws + (size_t)2 * 1024 * 1024);        // 2 MB
  unsigned short* hkb   = (unsigned short*)(ws + (size_t)4 * 1024 * 1024);        // 128 KB
  unsigned short* hvTb  = (unsigned short*)(ws + (size_t)4 * 1024 * 1024 + 131072);   // 128 KB
  unsigned short* Wk2b  = (unsigned short*)(ws + (size_t)4 * 1024 * 1024 + 262144);   // 256 KB
  unsigned short* Wv2Tb = (unsigned short*)(ws + (size_t)4 * 1024 * 1024 + 524288);   // 256 KB
  unsigned short* simw  = (unsigned short*)(ws + (size_t)8 * 1024 * 1024);        // 32 MB

  hipLaunchKernelGGL(token_h, dim3(256), dim3(256), 0, stream, tokens, Wk1, Wv1, hkb, hvTb);
  hipLaunchKernelGGL(prep_w, dim3(48), dim3(256), 0, stream, Wk2, Wv2, Wk2b, Wv2Tb);
  hipLaunchKernelGGL((skinny64<2048, true>), dim3(1024), dim3(256), 0, stream,
                     (const void*)x, Wk2b, xp);
  hipLaunchKernelGGL(simw_norm, dim3(512), dim3(256), 0, stream, xp, hkb, simw);
  hipLaunchKernelGGL((skinny64<1024, false>), dim3(1024), dim3(256), 0, stream,
                     (const void*)simw, hvTb, wv);
  hipLaunchKernelGGL(outk, dim3(512), dim3(256), 0, stream, wv, Wv2Tb, (float*)d_out);
}

// Round 7
// 138.432 us; speedup vs baseline: 1.9933x; 1.0392x over previous
//
#include <hip/hip_runtime.h>
#include <hip/hip_bf16.h>
#include <math.h>

typedef __attribute__((ext_vector_type(4))) float f32x4;
typedef __attribute__((ext_vector_type(8))) short bf16x8;     // 8 bf16 in 4 VGPRs
typedef __attribute__((ext_vector_type(4))) unsigned short u16x4;
typedef __attribute__((ext_vector_type(8))) unsigned short u16x8;
typedef __attribute__((ext_vector_type(2))) unsigned int u32x2;

__device__ __forceinline__ unsigned short f2b(float f) {
  unsigned int u = __builtin_bit_cast(unsigned int, f);
  u += 0x7fffu + ((u >> 16) & 1u);          // RNE
  return (unsigned short)(u >> 16);
}
__device__ __forceinline__ float b2f(unsigned short u) {
  unsigned int v = ((unsigned int)u) << 16;
  return __builtin_bit_cast(float, v);
}
__device__ __forceinline__ float gelu_exact(float x) {
  return 0.5f * x * (1.0f + erff(x * 0.70710678118654752440f));
}

// ---------------- token hidden + bf16 outputs ----------------
// hkb[t,j] = bf16(gelu(tokens@Wk1))  [1024,64]
// hvTb[j,t] = bf16(gelu(tokens@Wv1))ᵀ [64,1024]
__global__ void token_h(const float* __restrict__ tokens,
                        const float* __restrict__ Wk1, const float* __restrict__ Wv1,
                        unsigned short* __restrict__ hkb, unsigned short* __restrict__ hvTb) {
  __shared__ float tok[4][64];
  const int tid = threadIdx.x;
  const int tl = tid >> 6, j = tid & 63;
  const int t0 = blockIdx.x * 4;
  tok[tl][j] = tokens[(size_t)(t0 + tl) * 64 + j];
  __syncthreads();
  float sk = 0.f, sv = 0.f;
  #pragma unroll 16
  for (int i = 0; i < 64; ++i) {
    float tv = tok[tl][i];
    sk += tv * Wk1[i * 64 + j];
    sv += tv * Wv1[i * 64 + j];
  }
  hkb[(size_t)(t0 + tl) * 64 + j]  = f2b(gelu_exact(sk));
  hvTb[(size_t)j * 1024 + t0 + tl] = f2b(gelu_exact(sv));
}

// ---------------- prep: Wk2 -> bf16 [64,2048]; Wv2 [64,2048] -> Wv2T bf16 [2048,64] ----------------
__global__ void prep_w(const float* __restrict__ Wk2, const float* __restrict__ Wv2,
                       unsigned short* __restrict__ Wk2b, unsigned short* __restrict__ Wv2Tb) {
  const int tid = threadIdx.x;
  if (blockIdx.x < 16) {
    for (int i = 0; i < 8; ++i) {
      int idx = blockIdx.x * 2048 + i * 256 + tid;          // coalesced
      f32x4 v = ((const f32x4*)Wk2)[idx];
      u16x4 o; o[0] = f2b(v[0]); o[1] = f2b(v[1]); o[2] = f2b(v[2]); o[3] = f2b(v[3]);
      ((u16x4*)Wk2b)[idx] = o;
    }
  } else {
    __shared__ float t[64][65];
    const int f0 = (blockIdx.x - 16) * 64;
    for (int i = 0; i < 16; ++i) {
      int idx = i * 256 + tid; int r = idx >> 6, c = idx & 63;   // r=j, c=f
      t[r][c] = Wv2[(size_t)r * 2048 + f0 + c];
    }
    __syncthreads();
    for (int i = 0; i < 16; ++i) {
      int idx = i * 256 + tid; int r = idx >> 6, c = idx & 63;   // r=f, c=j
      Wv2Tb[(size_t)(f0 + r) * 64 + c] = f2b(t[c][r]);
    }
  }
}

// ---------------- skinny GEMM: out[M,64] bf16 = A[M,K] @ B[64,K]^T ----------------
// 16-row blocks, 4 waves split K into quarters, LDS cross-wave reduce.
template<int K, bool AF32>
__global__ __launch_bounds__(256)
void skinny64(const void* __restrict__ Aptr, const unsigned short* __restrict__ Bb,
              unsigned short* __restrict__ outp) {
  __shared__ float red[4][4][64][4];
  const int tid = threadIdx.x;
  const int wave = tid >> 6, lane = tid & 63;
  const int lrow = lane & 15, q = lane >> 4;
  const int r0 = blockIdx.x * 16;
  constexpr int KQ = K / 4;
  constexpr int NSTEP = KQ / 64;
  const int kbase = wave * KQ;

  f32x4 acc[4] = {};

  #pragma unroll 2
  for (int s = 0; s < NSTEP; ++s) {
    const int k0 = kbase + s * 64;
    bf16x8 a[2];
    if constexpr (AF32) {
      const float* A = (const float*)Aptr;
      #pragma unroll
      for (int kk = 0; kk < 2; ++kk) {
        const float* p = &A[(size_t)(r0 + lrow) * K + k0 + kk * 32 + q * 8];
        f32x4 lo = *(const f32x4*)p;
        f32x4 hi = *(const f32x4*)(p + 4);
        u16x8 t;
        t[0] = f2b(lo[0]); t[1] = f2b(lo[1]); t[2] = f2b(lo[2]); t[3] = f2b(lo[3]);
        t[4] = f2b(hi[0]); t[5] = f2b(hi[1]); t[6] = f2b(hi[2]); t[7] = f2b(hi[3]);
        a[kk] = __builtin_bit_cast(bf16x8, t);
      }
    } else {
      const unsigned short* A = (const unsigned short*)Aptr;
      #pragma unroll
      for (int kk = 0; kk < 2; ++kk)
        a[kk] = *(const bf16x8*)&A[(size_t)(r0 + lrow) * K + k0 + kk * 32 + q * 8];
    }
    #pragma unroll
    for (int nt = 0; nt < 4; ++nt) {
      #pragma unroll
      for (int kk = 0; kk < 2; ++kk) {
        bf16x8 b = *(const bf16x8*)&Bb[(size_t)(nt * 16 + lrow) * K + k0 + kk * 32 + q * 8];
        acc[nt] = __builtin_amdgcn_mfma_f32_16x16x32_bf16(a[kk], b, acc[nt], 0, 0, 0);
      }
    }
  }

  #pragma unroll
  for (int nt = 0; nt < 4; ++nt)
    *(f32x4*)&red[wave][nt][lane][0] = acc[nt];
  __syncthreads();
  if (wave == 0) {
    #pragma unroll
    for (int nt = 0; nt < 4; ++nt) {
      f32x4 s0 = *(const f32x4*)&red[0][nt][lane][0];
      f32x4 s1 = *(const f32x4*)&red[1][nt][lane][0];
      f32x4 s2 = *(const f32x4*)&red[2][nt][lane][0];
      f32x4 s3 = *(const f32x4*)&red[3][nt][lane][0];
      f32x4 s = s0 + s1 + s2 + s3;
      #pragma unroll
      for (int r = 0; r < 4; ++r)
        outp[(size_t)(r0 + q * 4 + r) * 64 + nt * 16 + lrow] = f2b(s[r]);
    }
  }
}

// ---------------- fused: wv[32,64] = gelu(rownorm(xp@hk^T)) @ hv, sim never hits HBM ----------------
// Swapped MFMA: acc = mfma(hk, xp) => simᵀ; lane (lrow,q) holds sim[row=lrow(+16mi)][tok=tw+t16*16+q*4+r].
// Row-sumsq: per-lane partial + shfl_xor(16,32) + cross-wave LDS. P=bf16(gelu(sim*scale)) ->
// wave-local LDS transpose buffer (row-major [32][1032], pad => 2-way-free banks) ->
// A-frags for wv=P@hvT^T with per-wave K-stripe, cross-wave LDS reduce.
__global__ __launch_bounds__(256)
void fused_simwv(const unsigned short* __restrict__ xp, const unsigned short* __restrict__ hkb,
                 const unsigned short* __restrict__ hvTb, unsigned short* __restrict__ wvout) {
  __shared__ unsigned short Pl[32][1032];          // 66 KB (stride 2064 B: banks 2-way only)
  __shared__ float redn[4][2][16];                 // norm partials
  __shared__ float redw[4][2][4][64][4];           // wv partials (32 KB)
  const int tid = threadIdx.x;
  const int wave = tid >> 6, lane = tid & 63;
  const int lrow = lane & 15, q = lane >> 4;
  const int r0 = blockIdx.x * 32;
  const int tw = wave * 256;                       // this wave's token stripe

  // B-frags: the 32 sim rows of xp
  bf16x8 xb[2][2];
  #pragma unroll
  for (int mi = 0; mi < 2; ++mi)
    #pragma unroll
    for (int kk = 0; kk < 2; ++kk)
      xb[mi][kk] = *(const bf16x8*)&xp[(size_t)(r0 + mi * 16 + lrow) * 64 + kk * 32 + q * 8];

  // simᵀ: acc[t16][mi], D[tok][row]
  f32x4 acc[16][2] = {};
  #pragma unroll
  for (int t16 = 0; t16 < 16; ++t16) {
    #pragma unroll
    for (int kk = 0; kk < 2; ++kk) {
      bf16x8 a = *(const bf16x8*)&hkb[(size_t)(tw + t16 * 16 + lrow) * 64 + kk * 32 + q * 8];
      #pragma unroll
      for (int mi = 0; mi < 2; ++mi)
        acc[t16][mi] = __builtin_amdgcn_mfma_f32_16x16x32_bf16(a, xb[mi][kk], acc[t16][mi], 0, 0, 0);
    }
  }

  // row sum-of-squares (row = mi*16 + lrow)
  float ss[2] = {0.f, 0.f};
  #pragma unroll
  for (int t16 = 0; t16 < 16; ++t16)
    #pragma unroll
    for (int mi = 0; mi < 2; ++mi)
      #pragma unroll
      for (int r = 0; r < 4; ++r)
        ss[mi] += acc[t16][mi][r] * acc[t16][mi][r];
  #pragma unroll
  for (int mi = 0; mi < 2; ++mi) {
    ss[mi] += __shfl_xor(ss[mi], 16, 64);
    ss[mi] += __shfl_xor(ss[mi], 32, 64);
  }
  if (q == 0) { redn[wave][0][lrow] = ss[0]; redn[wave][1][lrow] = ss[1]; }
  __syncthreads();
  float scale[2];
  #pragma unroll
  for (int mi = 0; mi < 2; ++mi) {
    float t = redn[0][mi][lrow] + redn[1][mi][lrow] + redn[2][mi][lrow] + redn[3][mi][lrow];
    scale[mi] = 32.0f * rsqrtf(fmaxf(t, 1e-20f));
  }

  // P = bf16(gelu(sim*scale)) -> LDS row-major (wave-local region: cols [tw, tw+256))
  #pragma unroll
  for (int t16 = 0; t16 < 16; ++t16)
    #pragma unroll
    for (int mi = 0; mi < 2; ++mi) {
      float g0 = gelu_exact(acc[t16][mi][0] * scale[mi]);
      float g1 = gelu_exact(acc[t16][mi][1] * scale[mi]);
      float g2 = gelu_exact(acc[t16][mi][2] * scale[mi]);
      float g3 = gelu_exact(acc[t16][mi][3] * scale[mi]);
      u32x2 pw;
      pw[0] = (unsigned)f2b(g0) | ((unsigned)f2b(g1) << 16);
      pw[1] = (unsigned)f2b(g2) | ((unsigned)f2b(g3) << 16);
      *(u32x2*)&Pl[mi * 16 + lrow][tw + t16 * 16 + q * 4] = pw;
    }
  __syncthreads();

  // wv partial over this wave's 256-token stripe
  f32x4 wva[2][4] = {};
  #pragma unroll
  for (int ks = 0; ks < 8; ++ks) {
    bf16x8 pa0 = *(const bf16x8*)&Pl[lrow][tw + ks * 32 + q * 8];
    bf16x8 pa1 = *(const bf16x8*)&Pl[16 + lrow][tw + ks * 32 + q * 8];
    #pragma unroll
    for (int nt = 0; nt < 4; ++nt) {
      bf16x8 b = *(const bf16x8*)&hvTb[(size_t)(nt * 16 + lrow) * 1024 + tw + ks * 32 + q * 8];
      wva[0][nt] = __builtin_amdgcn_mfma_f32_16x16x32_bf16(pa0, b, wva[0][nt], 0, 0, 0);
      wva[1][nt] = __builtin_amdgcn_mfma_f32_16x16x32_bf16(pa1, b, wva[1][nt], 0, 0, 0);
    }
  }

  // cross-wave K-reduce; wave w owns j-tile nt=w
  #pragma unroll
  for (int mi2 = 0; mi2 < 2; ++mi2)
    #pragma unroll
    for (int nt = 0; nt < 4; ++nt)
      *(f32x4*)&redw[wave][mi2][nt][lane][0] = wva[mi2][nt];
  __syncthreads();
  #pragma unroll
  for (int mi2 = 0; mi2 < 2; ++mi2) {
    f32x4 s = *(const f32x4*)&redw[0][mi2][wave][lane][0];
    s += *(const f32x4*)&redw[1][mi2][wave][lane][0];
    s += *(const f32x4*)&redw[2][mi2][wave][lane][0];
    s += *(const f32x4*)&redw[3][mi2][wave][lane][0];
    #pragma unroll
    for (int r = 0; r < 4; ++r)
      wvout[(size_t)(r0 + mi2 * 16 + q * 4 + r) * 64 + wave * 16 + lrow] = f2b(s[r]);
  }
}

// ---------------- out[16384,2048] f32 = wv[16384,64] @ Wv2T[2048,64]^T ----------------
__global__ __launch_bounds__(256)
void outk(const unsigned short* __restrict__ wv, const unsigned short* __restrict__ Wv2Tb,
          float* __restrict__ out) {
  const int tid = threadIdx.x;
  const int wave = tid >> 6, lane = tid & 63;
  const int lrow = lane & 15, q = lane >> 4;
  const int r0 = blockIdx.x * 32;
  const int c0 = wave * 512;

  bf16x8 a[2][2];
  #pragma unroll
  for (int mi = 0; mi < 2; ++mi)
    #pragma unroll
    for (int kk = 0; kk < 2; ++kk)
      a[mi][kk] = *(const bf16x8*)&wv[(size_t)(r0 + mi * 16 + lrow) * 64 + kk * 32 + q * 8];

  #pragma unroll 1
  for (int nf = 0; nf < 4; ++nf) {
    f32x4 acc[2][8] = {};
    #pragma unroll
    for (int nt = 0; nt < 8; ++nt) {
      const int frow = c0 + nf * 128 + nt * 16 + lrow;
      bf16x8 b0 = *(const bf16x8*)&Wv2Tb[(size_t)frow * 64 + q * 8];
      bf16x8 b1 = *(const bf16x8*)&Wv2Tb[(size_t)frow * 64 + 32 + q * 8];
      #pragma unroll
      for (int mi = 0; mi < 2; ++mi) {
        acc[mi][nt] = __builtin_amdgcn_mfma_f32_16x16x32_bf16(a[mi][0], b0, acc[mi][nt], 0, 0, 0);
        acc[mi][nt] = __builtin_amdgcn_mfma_f32_16x16x32_bf16(a[mi][1], b1, acc[mi][nt], 0, 0, 0);
      }
    }
    #pragma unroll
    for (int mi = 0; mi < 2; ++mi)
      #pragma unroll
      for (int nt = 0; nt < 8; ++nt)
        #pragma unroll
        for (int r = 0; r < 4; ++r)
          out[(size_t)(r0 + mi * 16 + q * 4 + r) * 2048 + c0 + nf * 128 + nt * 16 + lrow] =
              acc[mi][nt][r];
  }
}

extern "C" void kernel_launch(void* const* d_in, const int* in_sizes, int n_in,
                              void* d_out, int out_size, void* d_ws, size_t ws_size,
                              hipStream_t stream) {
  (void)in_sizes; (void)n_in; (void)out_size; (void)ws_size;
  const float* x      = (const float*)d_in[0];
  const float* tokens = (const float*)d_in[1];
  const float* Wk1    = (const float*)d_in[2];
  const float* Wk2    = (const float*)d_in[3];
  const float* Wv1    = (const float*)d_in[4];
  const float* Wv2    = (const float*)d_in[5];

  char* ws = (char*)d_ws;
  unsigned short* xp    = (unsigned short*)(ws);                                  // 2 MB
  unsigned short* wv    = (unsigned short*)(ws + (size_t)2 * 1024 * 1024);        // 2 MB
  unsigned short* hkb   = (unsigned short*)(ws + (size_t)4 * 1024 * 1024);        // 128 KB
  unsigned short* hvTb  = (unsigned short*)(ws + (size_t)4 * 1024 * 1024 + 131072);   // 128 KB
  unsigned short* Wk2b  = (unsigned short*)(ws + (size_t)4 * 1024 * 1024 + 262144);   // 256 KB
  unsigned short* Wv2Tb = (unsigned short*)(ws + (size_t)4 * 1024 * 1024 + 524288);   // 256 KB

  hipLaunchKernelGGL(token_h, dim3(256), dim3(256), 0, stream, tokens, Wk1, Wv1, hkb, hvTb);
  hipLaunchKernelGGL(prep_w, dim3(48), dim3(256), 0, stream, Wk2, Wv2, Wk2b, Wv2Tb);
  hipLaunchKernelGGL((skinny64<2048, true>), dim3(1024), dim3(256), 0, stream,
                     (const void*)x, Wk2b, xp);
  hipLaunchKernelGGL(fused_simwv, dim3(512), dim3(256), 0, stream, xp, hkb, hvTb, wv);
  hipLaunchKernelGGL(outk, dim3(512), dim3(256), 0, stream, wv, Wv2Tb, (float*)d_out);
}

// Round 8
// 122.193 us; speedup vs baseline: 2.2581x; 1.1329x over previous
//
#include <hip/hip_runtime.h>
#include <hip/hip_bf16.h>
#include <math.h>

typedef __attribute__((ext_vector_type(4))) float f32x4;
typedef __attribute__((ext_vector_type(8))) short bf16x8;     // 8 bf16 in 4 VGPRs
typedef __attribute__((ext_vector_type(4))) unsigned short u16x4;
typedef __attribute__((ext_vector_type(8))) unsigned short u16x8;
typedef __attribute__((ext_vector_type(2))) unsigned int u32x2;

__device__ __forceinline__ unsigned short f2b(float f) {
  unsigned int u = __builtin_bit_cast(unsigned int, f);
  u += 0x7fffu + ((u >> 16) & 1u);          // RNE
  return (unsigned short)(u >> 16);
}
__device__ __forceinline__ float gelu_exact(float x) {
  return 0.5f * x * (1.0f + erff(x * 0.70710678118654752440f));
}

// ---------------- prep: token MLP hiddens + weight conversions (one small kernel) ----
// hkb [1024,64] bf16 = gelu(tokens@Wk1); hvTb [64,1024] bf16 = gelu(tokens@Wv1)^T
// Wk2b [64,2048] bf16 copy; Wv2Tb [2048,64] bf16 transpose.
__global__ void prep(const float* __restrict__ tokens,
                     const float* __restrict__ Wk1, const float* __restrict__ Wv1,
                     const float* __restrict__ Wk2, const float* __restrict__ Wv2,
                     unsigned short* __restrict__ hkb, unsigned short* __restrict__ hvTb,
                     unsigned short* __restrict__ Wk2b, unsigned short* __restrict__ Wv2Tb) {
  const int tid = threadIdx.x;
  const int bx = blockIdx.x;
  if (bx < 256) {
    // token hidden: 4 tokens/block
    __shared__ float tok[4][64];
    const int tl = tid >> 6, j = tid & 63;
    const int t0 = bx * 4;
    tok[tl][j] = tokens[(size_t)(t0 + tl) * 64 + j];
    __syncthreads();
    float sk = 0.f, sv = 0.f;
    #pragma unroll 16
    for (int i = 0; i < 64; ++i) {
      float tv = tok[tl][i];
      sk += tv * Wk1[i * 64 + j];
      sv += tv * Wv1[i * 64 + j];
    }
    hkb[(size_t)(t0 + tl) * 64 + j]  = f2b(gelu_exact(sk));
    hvTb[(size_t)j * 1024 + t0 + tl] = f2b(gelu_exact(sv));
  } else if (bx < 272) {
    // Wk2 f32 -> bf16 (coalesced vec4)
    const int b = bx - 256;
    for (int i = 0; i < 8; ++i) {
      int idx = b * 2048 + i * 256 + tid;
      f32x4 v = ((const f32x4*)Wk2)[idx];
      u16x4 o; o[0] = f2b(v[0]); o[1] = f2b(v[1]); o[2] = f2b(v[2]); o[3] = f2b(v[3]);
      ((u16x4*)Wk2b)[idx] = o;
    }
  } else {
    // Wv2 [64,2048] -> Wv2T [2048,64] bf16, 64-col tile
    __shared__ float t[64][65];
    const int f0 = (bx - 272) * 64;
    for (int i = 0; i < 16; ++i) {
      int idx = i * 256 + tid; int r = idx >> 6, c = idx & 63;   // r=j, c=f
      t[r][c] = Wv2[(size_t)r * 2048 + f0 + c];
    }
    __syncthreads();
    for (int i = 0; i < 16; ++i) {
      int idx = i * 256 + tid; int r = idx >> 6, c = idx & 63;   // r=f, c=j
      Wv2Tb[(size_t)(f0 + r) * 64 + c] = f2b(t[c][r]);
    }
  }
}

// ---------------- main: x[16 rows] -> xp -> sim -> norm/gelu -> wv -> out, one pass ----
// 1024 blocks x 256 thr, 16 x-rows per block. All intermediates in regs/LDS.
// Phase 1: xp16 = x16 @ Wk2b^T (wave K-split 4x512, LDS reduce)
// Phase 2: simT stripe: acc[t16] = mfma(hk rows, xp rows)  (lane: sim row=lrow, 64 tokens)
// Phase 3: row sumsq (shfl q-bits + cross-wave LDS) -> scale
// Phase 4: P = bf16(gelu(sim*scale)) -> wave-private LDS chunks -> wv partial (MFMA)
// Phase 5: wv cross-wave LDS reduce -> wv16 bf16
// Phase 6: out16x2048 = wv16 @ Wv2T^T, f32 stores
__global__ __launch_bounds__(256, 4)
void mainK(const float* __restrict__ x,
           const unsigned short* __restrict__ Wk2b,
           const unsigned short* __restrict__ hkb,
           const unsigned short* __restrict__ hvTb,
           const unsigned short* __restrict__ Wv2Tb,
           float* __restrict__ out) {
  __shared__ float redbuf[4][4][64][4];          // 16 KB: xp partials, later wv partials
  __shared__ unsigned short Pl[4][16][152];      // 19 KB: wave-private P chunks (stride 304B: 16B-mult, conflict-light)
  __shared__ unsigned short xw16[16][72];        // 2.3 KB: xp16, later wv16 (stride 144B)
  __shared__ float redn[4][16];                  // norm partials

  const int tid = threadIdx.x;
  const int wave = tid >> 6, lane = tid & 63;
  const int lrow = lane & 15, q = lane >> 4;
  const int r0 = blockIdx.x * 16;
  const int tw = wave * 256;                     // wave's token stripe

  // ---- phase 1: xp ----
  {
    f32x4 accp[4] = {};
    const int kbase = wave * 512;
    #pragma unroll 2
    for (int s = 0; s < 8; ++s) {
      const int k0 = kbase + s * 64;
      bf16x8 a[2];
      #pragma unroll
      for (int kk = 0; kk < 2; ++kk) {
        const float* p = &x[(size_t)(r0 + lrow) * 2048 + k0 + kk * 32 + q * 8];
        f32x4 lo = *(const f32x4*)p;
        f32x4 hi = *(const f32x4*)(p + 4);
        u16x8 t;
        t[0] = f2b(lo[0]); t[1] = f2b(lo[1]); t[2] = f2b(lo[2]); t[3] = f2b(lo[3]);
        t[4] = f2b(hi[0]); t[5] = f2b(hi[1]); t[6] = f2b(hi[2]); t[7] = f2b(hi[3]);
        a[kk] = __builtin_bit_cast(bf16x8, t);
      }
      #pragma unroll
      for (int nt = 0; nt < 4; ++nt)
        #pragma unroll
        for (int kk = 0; kk < 2; ++kk) {
          bf16x8 b = *(const bf16x8*)&Wk2b[(size_t)(nt * 16 + lrow) * 2048 + k0 + kk * 32 + q * 8];
          accp[nt] = __builtin_amdgcn_mfma_f32_16x16x32_bf16(a[kk], b, accp[nt], 0, 0, 0);
        }
    }
    #pragma unroll
    for (int nt = 0; nt < 4; ++nt)
      *(f32x4*)&redbuf[wave][nt][lane][0] = accp[nt];
  }
  __syncthreads();
  {
    // wave w reduces xp cols w*16..w*16+15
    f32x4 s = *(const f32x4*)&redbuf[0][wave][lane][0];
    s += *(const f32x4*)&redbuf[1][wave][lane][0];
    s += *(const f32x4*)&redbuf[2][wave][lane][0];
    s += *(const f32x4*)&redbuf[3][wave][lane][0];
    #pragma unroll
    for (int r = 0; r < 4; ++r)
      xw16[q * 4 + r][wave * 16 + lrow] = f2b(s[r]);   // xp16[row][col]
  }
  __syncthreads();

  // ---- phase 2: simT for this wave's 256-token stripe ----
  bf16x8 xb[2];
  #pragma unroll
  for (int kk = 0; kk < 2; ++kk)
    xb[kk] = *(const bf16x8*)&xw16[lrow][kk * 32 + q * 8];   // B-frag: xp row = lrow
  f32x4 acc[16] = {};
  #pragma unroll
  for (int t16 = 0; t16 < 16; ++t16)
    #pragma unroll
    for (int kk = 0; kk < 2; ++kk) {
      bf16x8 a = *(const bf16x8*)&hkb[(size_t)(tw + t16 * 16 + lrow) * 64 + kk * 32 + q * 8];
      acc[t16] = __builtin_amdgcn_mfma_f32_16x16x32_bf16(a, xb[kk], acc[t16], 0, 0, 0);
    }

  // ---- phase 3: row sumsq -> scale (sim row = lrow) ----
  float ss = 0.f;
  #pragma unroll
  for (int t16 = 0; t16 < 16; ++t16)
    #pragma unroll
    for (int r = 0; r < 4; ++r)
      ss += acc[t16][r] * acc[t16][r];
  ss += __shfl_xor(ss, 16, 64);
  ss += __shfl_xor(ss, 32, 64);
  if (q == 0) redn[wave][lrow] = ss;
  __syncthreads();
  const float scale = 32.0f * rsqrtf(fmaxf(
      redn[0][lrow] + redn[1][lrow] + redn[2][lrow] + redn[3][lrow], 1e-20f));

  // ---- phase 4: P chunks (gelu) + wv partial ----
  f32x4 wva[4] = {};
  #pragma unroll
  for (int c = 0; c < 2; ++c) {
    #pragma unroll
    for (int t8 = 0; t8 < 8; ++t8) {
      const int t16 = c * 8 + t8;
      float g0 = gelu_exact(acc[t16][0] * scale);
      float g1 = gelu_exact(acc[t16][1] * scale);
      float g2 = gelu_exact(acc[t16][2] * scale);
      float g3 = gelu_exact(acc[t16][3] * scale);
      u32x2 pw;
      pw[0] = (unsigned)f2b(g0) | ((unsigned)f2b(g1) << 16);
      pw[1] = (unsigned)f2b(g2) | ((unsigned)f2b(g3) << 16);
      *(u32x2*)&Pl[wave][lrow][t8 * 16 + q * 4] = pw;        // chunk-local token t8*16+q*4
    }
    #pragma unroll
    for (int kc = 0; kc < 4; ++kc) {
      bf16x8 pa = *(const bf16x8*)&Pl[wave][lrow][kc * 32 + q * 8];
      #pragma unroll
      for (int nt = 0; nt < 4; ++nt) {
        bf16x8 b = *(const bf16x8*)&hvTb[(size_t)(nt * 16 + lrow) * 1024 +
                                         tw + c * 128 + kc * 32 + q * 8];
        wva[nt] = __builtin_amdgcn_mfma_f32_16x16x32_bf16(pa, b, wva[nt], 0, 0, 0);
      }
    }
  }

  // ---- phase 5: wv cross-wave reduce -> wv16 (reuse redbuf, xw16) ----
  #pragma unroll
  for (int nt = 0; nt < 4; ++nt)
    *(f32x4*)&redbuf[wave][nt][lane][0] = wva[nt];
  __syncthreads();
  {
    f32x4 s = *(const f32x4*)&redbuf[0][wave][lane][0];
    s += *(const f32x4*)&redbuf[1][wave][lane][0];
    s += *(const f32x4*)&redbuf[2][wave][lane][0];
    s += *(const f32x4*)&redbuf[3][wave][lane][0];
    #pragma unroll
    for (int r = 0; r < 4; ++r)
      xw16[q * 4 + r][wave * 16 + lrow] = f2b(s[r]);   // wv16[row][j]
  }
  __syncthreads();

  // ---- phase 6: out = wv16 @ Wv2T^T (wave: 512-col stripe) ----
  bf16x8 aw[2];
  #pragma unroll
  for (int kk = 0; kk < 2; ++kk)
    aw[kk] = *(const bf16x8*)&xw16[lrow][kk * 32 + q * 8];
  const int c0 = wave * 512;
  #pragma unroll 1
  for (int nf = 0; nf < 4; ++nf) {
    f32x4 acc2[8] = {};
    #pragma unroll
    for (int nt = 0; nt < 8; ++nt) {
      const int frow = c0 + nf * 128 + nt * 16 + lrow;
      bf16x8 b0 = *(const bf16x8*)&Wv2Tb[(size_t)frow * 64 + q * 8];
      bf16x8 b1 = *(const bf16x8*)&Wv2Tb[(size_t)frow * 64 + 32 + q * 8];
      acc2[nt] = __builtin_amdgcn_mfma_f32_16x16x32_bf16(aw[0], b0, acc2[nt], 0, 0, 0);
      acc2[nt] = __builtin_amdgcn_mfma_f32_16x16x32_bf16(aw[1], b1, acc2[nt], 0, 0, 0);
    }
    #pragma unroll
    for (int nt = 0; nt < 8; ++nt)
      #pragma unroll
      for (int r = 0; r < 4; ++r)
        out[(size_t)(r0 + q * 4 + r) * 2048 + c0 + nf * 128 + nt * 16 + lrow] = acc2[nt][r];
  }
}

extern "C" void kernel_launch(void* const* d_in, const int* in_sizes, int n_in,
                              void* d_out, int out_size, void* d_ws, size_t ws_size,
                              hipStream_t stream) {
  (void)in_sizes; (void)n_in; (void)out_size; (void)ws_size;
  const float* x      = (const float*)d_in[0];
  const float* tokens = (const float*)d_in[1];
  const float* Wk1    = (const float*)d_in[2];
  const float* Wk2    = (const float*)d_in[3];
  const float* Wv1    = (const float*)d_in[4];
  const float* Wv2    = (const float*)d_in[5];

  char* ws = (char*)d_ws;
  unsigned short* hkb   = (unsigned short*)(ws);                    // 128 KB
  unsigned short* hvTb  = (unsigned short*)(ws + 131072);           // 128 KB
  unsigned short* Wk2b  = (unsigned short*)(ws + 262144);           // 256 KB
  unsigned short* Wv2Tb = (unsigned short*)(ws + 524288);           // 256 KB

  hipLaunchKernelGGL(prep, dim3(304), dim3(256), 0, stream,
                     tokens, Wk1, Wv1, Wk2, Wv2, hkb, hvTb, Wk2b, Wv2Tb);
  hipLaunchKernelGGL(mainK, dim3(1024), dim3(256), 0, stream,
                     x, Wk2b, hkb, hvTb, Wv2Tb, (float*)d_out);
}